// Round 2
// baseline (58.196 us; speedup 1.0000x reference)
//
#include <hip/hip_runtime.h>

#define BB 32
#define NN 2048
#define WW 64
#define CC 1024
#define NTAP 17
#define SCAL_STRIDE 96
#define EPSF 1e-8f

// ws layout (floats), per-batch stride SCAL_STRIDE:
//   [0..63]  k (tanh of projection)
//   [64]     beta (softplus)
//   [65]     gate (sigmoid)
//   [66..82] wd[17] tap weights, pre-multiplied by 1/(S+eps)

// ---------------------------------------------------------------------------
// K0: projections. 32 blocks x 1024. b = blockIdx.x.
// ---------------------------------------------------------------------------
__global__ __launch_bounds__(1024) void k_proj(
    const float* __restrict__ co,
    const float* __restrict__ Wk, const float* __restrict__ bk,
    const float* __restrict__ Wb, const float* __restrict__ bb,
    const float* __restrict__ Ws, const float* __restrict__ bs,
    const float* __restrict__ Wg, const float* __restrict__ bg,
    float* __restrict__ scal)
{
    __shared__ float co_s[CC];
    __shared__ float logits[80];
    const int tid = threadIdx.x;
    const int b = blockIdx.x;
    for (int i = tid; i < CC; i += 1024) co_s[i] = co[(size_t)b * CC + i];
    __syncthreads();
    const int wave = tid >> 6, lane = tid & 63;
    for (int o = wave; o < 69; o += 16) {
        const float* row; float bias;
        if (o < 64)      { row = Wk + (size_t)o * CC; bias = bk[o]; }
        else if (o == 64){ row = Wb;                  bias = bb[0]; }
        else if (o < 68) { row = Ws + (size_t)(o - 65) * CC; bias = bs[o - 65]; }
        else             { row = Wg;                  bias = bg[0]; }
        float s = 0.f;
        for (int c = lane; c < CC; c += 64) s = fmaf(co_s[c], row[c], s);
        #pragma unroll
        for (int off = 32; off; off >>= 1) s += __shfl_xor(s, off);
        if (lane == 0) logits[o] = s + bias;
    }
    __syncthreads();
    float* sb = scal + (size_t)b * SCAL_STRIDE;
    if (tid < 64) {
        sb[tid] = tanhf(logits[tid]);
    } else if (tid == 64) {
        float x = logits[64];                       // beta = softplus
        sb[64] = (x > 20.f) ? x : log1pf(__expf(x));
    } else if (tid == 65) {
        float x = logits[68];                       // gate = sigmoid
        sb[65] = 1.f / (1.f + __expf(-x));
    } else if (tid == 66) {
        float s0 = logits[65], s1 = logits[66], s2 = logits[67];
        float m = fmaxf(s0, fmaxf(s1, s2));
        float ex0 = __expf(s0 - m), ex1 = __expf(s1 - m), ex2 = __expf(s2 - m);
        float inv = 1.f / (ex0 + ex1 + ex2);
        float sc = (ex2 - ex0) * inv;               // -shift0 + shift2
        float den = 2.f * sc * sc + EPSF;
        float wd[NTAP]; float S = 0.f;
        #pragma unroll
        for (int d = 0; d < NTAP; d++) {
            wd[d] = __expf(-(float)(d * d) / den);
            S += wd[d];
        }
        float invS = 1.f / (S + EPSF);
        #pragma unroll
        for (int d = 0; d < NTAP; d++) sb[66 + d] = wd[d] * invS;
    }
}

// ---------------------------------------------------------------------------
// K1: 512 blocks x 1024, interleaved by parity so each CU gets ~one of each:
//   even blocks (idx = blk>>1): allocation via masked log-sum (sort-free)
//   odd  blocks: sim[b,n] = memory[b,n,:]·k[b,:] -> staged in d_out slot 0
// alloc[i] = exp( sum_{(u_j,j) <=lex (u_i,i)} log1p(-u_j) )
//   (u64 key (bits(u)<<32)|j: u in [0,1) positive => bit order == value order;
//    matches jnp stable argsort + inclusive cumprod + scatter exactly, incl. ties)
// ---------------------------------------------------------------------------
__global__ __launch_bounds__(1024) void k_main(
    const float* __restrict__ usage, const float* __restrict__ mem,
    const float* __restrict__ scal,
    float* __restrict__ alloc_out, float* __restrict__ sim)
{
    __shared__ __align__(16) unsigned long long skey[NN];  // 16 KB
    __shared__ __align__(16) float sL[NN];                 // 8 KB
    __shared__ float partial[16][256];                     // 16 KB
    const int tid = threadIdx.x;
    const int idx = blockIdx.x >> 1;

    if ((blockIdx.x & 1) == 0) {
        // ================= allocation =================
        const int b = idx >> 3, s = idx & 7;   // 8 blocks/batch, 256 elems each
        for (int j = tid; j < NN; j += 1024) {
            float u = usage[(size_t)b * NN + j];
            skey[j] = ((unsigned long long)__float_as_uint(u) << 32) | (unsigned)j;
            sL[j]   = log1pf(-u);
        }
        __syncthreads();
        const int wave = tid >> 6, lane = tid & 63;
        unsigned long long myk[4];
        float sum[4] = {0.f, 0.f, 0.f, 0.f};
        #pragma unroll
        for (int k = 0; k < 4; k++) myk[k] = skey[s * 256 + k * 64 + lane];
        const int j0 = wave * 128;             // each wave scans 128 j's
        #pragma unroll 4
        for (int jj = 0; jj < 128; jj += 2) {
            ulonglong2 kj = *(const ulonglong2*)&skey[j0 + jj];   // broadcast
            float2     lj = *(const float2*)&sL[j0 + jj];
            #pragma unroll
            for (int k = 0; k < 4; k++) {
                sum[k] += (kj.x <= myk[k]) ? lj.x : 0.f;
                sum[k] += (kj.y <= myk[k]) ? lj.y : 0.f;
            }
        }
        #pragma unroll
        for (int k = 0; k < 4; k++) partial[wave][k * 64 + lane] = sum[k];
        __syncthreads();
        const int e = tid >> 2, q = tid & 3;
        float tot = partial[q * 4 + 0][e] + partial[q * 4 + 1][e]
                  + partial[q * 4 + 2][e] + partial[q * 4 + 3][e];
        tot += __shfl_xor(tot, 1);
        tot += __shfl_xor(tot, 2);
        if (q == 0) alloc_out[(size_t)b * NN + s * 256 + e] = expf(tot);
    } else {
        // ================= sim =================
        const int b = idx >> 3, seg = idx & 7;
        const int lane16 = tid & 15;
        const int group = tid >> 4;   // 0..63
        const float4 kv = *reinterpret_cast<const float4*>(
            scal + (size_t)b * SCAL_STRIDE + lane16 * 4);
        #pragma unroll
        for (int it = 0; it < 4; it++) {
            int row = seg * 256 + it * 64 + group;
            const float4 m4 = *reinterpret_cast<const float4*>(
                mem + ((size_t)b * NN + row) * WW + lane16 * 4);
            float sdot = m4.x * kv.x + m4.y * kv.y + m4.z * kv.z + m4.w * kv.w;
            sdot += __shfl_xor(sdot, 1); sdot += __shfl_xor(sdot, 2);
            sdot += __shfl_xor(sdot, 4); sdot += __shfl_xor(sdot, 8);
            if (lane16 == 0) sim[(size_t)b * NN + row] = sdot;
        }
    }
}

// ---------------------------------------------------------------------------
// K2: per-batch softmax(content) + 17-tap directional + combine
//     reads sim from slot0, alloc from slot3; writes slots 0,1,2
// ---------------------------------------------------------------------------
__global__ __launch_bounds__(1024) void k_post(
    const float* __restrict__ rdw, const float* __restrict__ scal,
    float* out)
{
    __shared__ float r_s[NN];
    __shared__ float wd_s[NTAP];
    __shared__ float red[16];
    __shared__ float bcast[2];
    const int b = blockIdx.x, tid = threadIdx.x;
    const float* sb = scal + (size_t)b * SCAL_STRIDE;
    const float beta = sb[64], gate = sb[65];
    if (tid < NTAP) wd_s[tid] = sb[66 + tid];
    r_s[tid]        = rdw[(size_t)b * NN + tid];
    r_s[tid + 1024] = rdw[(size_t)b * NN + tid + 1024];

    float s0 = out[(size_t)b * NN + tid] * beta;          // sim staged in slot0
    float s1 = out[(size_t)b * NN + tid + 1024] * beta;

    // block max
    float m = fmaxf(s0, s1);
    #pragma unroll
    for (int off = 32; off; off >>= 1) m = fmaxf(m, __shfl_xor(m, off));
    if ((tid & 63) == 0) red[tid >> 6] = m;
    __syncthreads();
    if (tid < 16) {
        float v = red[tid];
        v = fmaxf(v, __shfl_xor(v, 1)); v = fmaxf(v, __shfl_xor(v, 2));
        v = fmaxf(v, __shfl_xor(v, 4)); v = fmaxf(v, __shfl_xor(v, 8));
        if (tid == 0) bcast[0] = v;
    }
    __syncthreads();
    m = bcast[0];
    float e0 = __expf(s0 - m), e1 = __expf(s1 - m);
    float ssum = e0 + e1;
    #pragma unroll
    for (int off = 32; off; off >>= 1) ssum += __shfl_xor(ssum, off);
    if ((tid & 63) == 0) red[tid >> 6] = ssum;
    __syncthreads();
    if (tid < 16) {
        float v = red[tid];
        v += __shfl_xor(v, 1); v += __shfl_xor(v, 2);
        v += __shfl_xor(v, 4); v += __shfl_xor(v, 8);
        if (tid == 0) bcast[1] = v;
    }
    __syncthreads();
    const float inv = 1.f / bcast[1];
    const float c0 = e0 * inv, c1 = e1 * inv;
    out[(size_t)BB * NN + (size_t)b * NN + tid]        = c0;   // content
    out[(size_t)BB * NN + (size_t)b * NN + tid + 1024] = c1;

    // directional: dw[m] = sum_d wd[d] * r[(m + 1024 + d) & 2047]
    float dw0 = 0.f, dw1 = 0.f;
    #pragma unroll
    for (int d = 0; d < NTAP; d++) {
        float w = wd_s[d];
        dw0 = fmaf(w, r_s[(tid + 1024 + d) & (NN - 1)], dw0);
        dw1 = fmaf(w, r_s[(tid + d) & (NN - 1)], dw1);
    }
    out[2 * (size_t)BB * NN + (size_t)b * NN + tid]        = dw0;
    out[2 * (size_t)BB * NN + (size_t)b * NN + tid + 1024] = dw1;

    const float a0 = out[3 * (size_t)BB * NN + (size_t)b * NN + tid];
    const float a1 = out[3 * (size_t)BB * NN + (size_t)b * NN + tid + 1024];
    out[(size_t)b * NN + tid]        = gate * (0.5f * c0 + 0.5f * dw0 * a0);
    out[(size_t)b * NN + tid + 1024] = gate * (0.5f * c1 + 0.5f * dw1 * a1);
}

extern "C" void kernel_launch(void* const* d_in, const int* in_sizes, int n_in,
                              void* d_out, int out_size, void* d_ws, size_t ws_size,
                              hipStream_t stream) {
    const float* co    = (const float*)d_in[0];
    const float* rdw   = (const float*)d_in[1];
    const float* mem   = (const float*)d_in[3];
    const float* usage = (const float*)d_in[4];
    const float* Wk    = (const float*)d_in[5];
    const float* bk    = (const float*)d_in[6];
    const float* Wb    = (const float*)d_in[7];
    const float* bb    = (const float*)d_in[8];
    const float* Ws_   = (const float*)d_in[9];
    const float* bs    = (const float*)d_in[10];
    const float* Wg    = (const float*)d_in[11];
    const float* bg    = (const float*)d_in[12];
    float* out  = (float*)d_out;
    float* scal = (float*)d_ws;

    hipLaunchKernelGGL(k_proj, dim3(BB), dim3(1024), 0, stream,
                       co, Wk, bk, Wb, bb, Ws_, bs, Wg, bg, scal);
    hipLaunchKernelGGL(k_main, dim3(512), dim3(1024), 0, stream,
                       usage, mem, scal,
                       out + 3 * (size_t)BB * NN /* alloc */, out /* sim */);
    hipLaunchKernelGGL(k_post, dim3(BB), dim3(1024), 0, stream,
                       rdw, scal, out);
}

// Round 3
// 27.419 us; speedup vs baseline: 2.1225x; 2.1225x over previous
//
#include <hip/hip_runtime.h>

#define BB 32
#define NN 2048
#define WW 64
#define CC 1024
#define NTAP 17
#define NB 1024
#define EPSF 1e-8f

// ---------------------------------------------------------------------------
// K1: 256 blocks x 1024 threads. b = blk>>3, seg = blk&7.
// Recomputes k = tanh(co @ Wk^T + bk) per block (cheap, weights L2-hot),
// then sim[b, seg*256 .. seg*256+255] = memory rows · k  -> ws
// ---------------------------------------------------------------------------
__global__ __launch_bounds__(1024) void k_sim(
    const float* __restrict__ co, const float* __restrict__ mem,
    const float* __restrict__ Wk, const float* __restrict__ bk,
    float* __restrict__ sim_ws)
{
    __shared__ float co_s[CC];
    __shared__ __align__(16) float k_s[WW];
    const int tid = threadIdx.x;
    const int b = blockIdx.x >> 3, seg = blockIdx.x & 7;
    co_s[tid] = co[(size_t)b * CC + tid];
    __syncthreads();
    const int wave = tid >> 6, lane = tid & 63;
    for (int o = wave; o < WW; o += 16) {
        const float* row = Wk + (size_t)o * CC;
        float s = 0.f;
        #pragma unroll 4
        for (int c = lane; c < CC; c += 64) s = fmaf(co_s[c], row[c], s);
        #pragma unroll
        for (int off = 32; off; off >>= 1) s += __shfl_xor(s, off);
        if (lane == 0) k_s[o] = tanhf(s + bk[o]);
    }
    __syncthreads();
    const int lane16 = tid & 15, group = tid >> 4;
    const float4 kv = *reinterpret_cast<const float4*>(&k_s[lane16 * 4]);
    #pragma unroll
    for (int it = 0; it < 4; it++) {
        int row = seg * 256 + it * 64 + group;
        const float4 m4 = *reinterpret_cast<const float4*>(
            mem + ((size_t)b * NN + row) * WW + lane16 * 4);
        float s = m4.x * kv.x + m4.y * kv.y + m4.z * kv.z + m4.w * kv.w;
        s += __shfl_xor(s, 1); s += __shfl_xor(s, 2);
        s += __shfl_xor(s, 4); s += __shfl_xor(s, 8);
        if (lane16 == 0) sim_ws[(size_t)b * NN + row] = s;
    }
}

// ---------------------------------------------------------------------------
// K2: 32 blocks x 1024, one per batch. Small dots, counting-bin allocation,
// softmax, directional conv, combine. Everything in LDS.
// alloc[i] = exp( prefix_logsum(bins < bin(i)) + sum_{j in bin(i), key_j<=key_i} log1p(-u_j) )
// bin = floor(u*NB) is monotone in u => cross-bin order == value order; within
// bin the u64 key (bits<<32)|idx reproduces jnp's stable argsort exactly.
// ---------------------------------------------------------------------------
__global__ __launch_bounds__(1024) void k_rest(
    const float* __restrict__ co, const float* __restrict__ rdw,
    const float* __restrict__ usage, const float* __restrict__ sim_ws,
    const float* __restrict__ Wb, const float* __restrict__ bb,
    const float* __restrict__ Ws, const float* __restrict__ bs,
    const float* __restrict__ Wg, const float* __restrict__ bg,
    float* __restrict__ out)
{
    __shared__ float co_s[CC];                 // 4 KB
    __shared__ float r_s[NN];                  // 8 KB
    __shared__ float sim_s[NN];                // 8 KB
    __shared__ float alloc_s[NN];              // 8 KB
    __shared__ unsigned long long skey[NN];    // 16 KB
    __shared__ float slog[NN];                 // 8 KB
    __shared__ unsigned hist[NB];              // 4 KB
    __shared__ unsigned binStart[NB];          // 4 KB
    __shared__ unsigned cursor[NB];            // 4 KB
    __shared__ float binpre[NB];               // 4 KB
    __shared__ float wsum[16];
    __shared__ unsigned uw[16];
    __shared__ float red[16];
    __shared__ float bcast[2];
    __shared__ float scalars[8];               // 0=beta_logit 1..3=shift 4=gate_logit 5=beta 6=gate
    __shared__ float wd_s[NTAP];

    const int tid = threadIdx.x;
    const int b = blockIdx.x;
    const int wave = tid >> 6, lane = tid & 63;

    // ---- P0: loads ----
    co_s[tid] = co[(size_t)b * CC + tid];
    r_s[tid]          = rdw[(size_t)b * NN + tid];
    r_s[tid + 1024]   = rdw[(size_t)b * NN + tid + 1024];
    sim_s[tid]        = sim_ws[(size_t)b * NN + tid];
    sim_s[tid + 1024] = sim_ws[(size_t)b * NN + tid + 1024];
    hist[tid] = 0u;
    float u0 = usage[(size_t)b * NN + tid];
    float u1 = usage[(size_t)b * NN + tid + 1024];
    __syncthreads();
    unsigned long long key0 = ((unsigned long long)__float_as_uint(u0) << 32) | (unsigned)tid;
    unsigned long long key1 = ((unsigned long long)__float_as_uint(u1) << 32) | (unsigned)(tid + 1024);
    float lg0 = log1pf(-u0), lg1 = log1pf(-u1);
    int bin0 = (int)(u0 * NB); bin0 = bin0 < 0 ? 0 : (bin0 > NB - 1 ? NB - 1 : bin0);
    int bin1 = (int)(u1 * NB); bin1 = bin1 < 0 ? 0 : (bin1 > NB - 1 ? NB - 1 : bin1);
    atomicAdd(&hist[bin0], 1u);
    atomicAdd(&hist[bin1], 1u);

    // ---- P1: small dots (5 waves) ----
    if (wave < 5) {
        const float* row; float bias;
        if (wave == 0)      { row = Wb;                        bias = bb[0]; }
        else if (wave < 4)  { row = Ws + (size_t)(wave - 1) * CC; bias = bs[wave - 1]; }
        else                { row = Wg;                        bias = bg[0]; }
        float s = 0.f;
        #pragma unroll 4
        for (int c = lane; c < CC; c += 64) s = fmaf(co_s[c], row[c], s);
        #pragma unroll
        for (int off = 32; off; off >>= 1) s += __shfl_xor(s, off);
        if (lane == 0) scalars[wave] = s + bias;
    }
    __syncthreads();
    if (tid == 0) {
        float x = scalars[0];
        scalars[5] = (x > 20.f) ? x : log1pf(__expf(x));   // beta
        float g = scalars[4];
        scalars[6] = 1.f / (1.f + __expf(-g));             // gate
        float s0 = scalars[1], s1 = scalars[2], s2 = scalars[3];
        float m = fmaxf(s0, fmaxf(s1, s2));
        float e0 = __expf(s0 - m), e1 = __expf(s1 - m), e2 = __expf(s2 - m);
        float inv = 1.f / (e0 + e1 + e2);
        float sc = (e2 - e0) * inv;
        float den = 2.f * sc * sc + EPSF;
        float w[NTAP]; float S = 0.f;
        #pragma unroll
        for (int d = 0; d < NTAP; d++) { w[d] = __expf(-(float)(d * d) / den); S += w[d]; }
        float invS = 1.f / (S + EPSF);
        #pragma unroll
        for (int d = 0; d < NTAP; d++) wd_s[d] = w[d] * invS;
    }
    __syncthreads();

    // ---- P2: exclusive scan of hist -> binStart, cursor (tid == bin) ----
    unsigned hv = hist[tid];
    unsigned inc = hv;
    #pragma unroll
    for (int off = 1; off < 64; off <<= 1) {
        unsigned t = __shfl_up(inc, off);
        if (lane >= off) inc += t;
    }
    if (lane == 63) uw[wave] = inc;
    __syncthreads();
    if (tid < 16) {
        unsigned v = uw[tid];
        #pragma unroll
        for (int off = 1; off < 16; off <<= 1) {
            unsigned t = __shfl_up(v, off);
            if (tid >= off) v += t;
        }
        uw[tid] = v;
    }
    __syncthreads();
    {
        unsigned woff = (wave > 0) ? uw[wave - 1] : 0u;
        unsigned ex = __shfl_up(inc, 1);
        if (lane == 0) ex = 0u;
        unsigned st = woff + ex;
        binStart[tid] = st;
        cursor[tid] = st;
    }
    __syncthreads();

    // ---- P3: scatter into bin segments ----
    {
        unsigned p0 = atomicAdd(&cursor[bin0], 1u);
        skey[p0] = key0; slog[p0] = lg0;
        unsigned p1 = atomicAdd(&cursor[bin1], 1u);
        skey[p1] = key1; slog[p1] = lg1;
    }
    __syncthreads();

    // ---- P4: per-bin log-sums, exclusive float scan -> binpre ----
    {
        unsigned st = binStart[tid], cnt = hist[tid];
        float bsum = 0.f;
        for (unsigned i = 0; i < cnt; i++) bsum += slog[st + i];
        float finc = bsum;
        #pragma unroll
        for (int off = 1; off < 64; off <<= 1) {
            float t = __shfl_up(finc, off);
            if (lane >= off) finc += t;
        }
        if (lane == 63) wsum[wave] = finc;
        __syncthreads();
        if (tid < 16) {
            float v = wsum[tid];
            #pragma unroll
            for (int off = 1; off < 16; off <<= 1) {
                float t = __shfl_up(v, off);
                if (tid >= off) v += t;
            }
            wsum[tid] = v;
        }
        __syncthreads();
        float fwoff = (wave > 0) ? wsum[wave - 1] : 0.f;
        float fex = __shfl_up(finc, 1);
        if (lane == 0) fex = 0.f;
        binpre[tid] = fwoff + fex;
    }
    __syncthreads();

    // ---- P5: per-position masked sums -> alloc ----
    #pragma unroll
    for (int pp = 0; pp < 2; pp++) {
        int p = tid + pp * 1024;
        unsigned long long kp = skey[p];
        float up = __uint_as_float((unsigned)(kp >> 32));
        int c = (int)(up * NB); c = c < 0 ? 0 : (c > NB - 1 ? NB - 1 : c);
        unsigned st = binStart[c], cnt = hist[c];
        float s = binpre[c];
        for (unsigned q = 0; q < cnt; q++) {
            unsigned long long kq = skey[st + q];
            s += (kq <= kp) ? slog[st + q] : 0.f;
        }
        float a = expf(s);
        unsigned idx = (unsigned)(kp & 0xFFFFFFFFu);
        alloc_s[idx] = a;
        out[3 * (size_t)BB * NN + (size_t)b * NN + idx] = a;
    }

    // ---- P6: softmax over beta*sim ----
    const float beta = scalars[5], gate = scalars[6];
    float s0v = sim_s[tid] * beta, s1v = sim_s[tid + 1024] * beta;
    float m = fmaxf(s0v, s1v);
    #pragma unroll
    for (int off = 32; off; off >>= 1) m = fmaxf(m, __shfl_xor(m, off));
    if (lane == 0) red[wave] = m;
    __syncthreads();
    if (tid < 16) {
        float v = red[tid];
        v = fmaxf(v, __shfl_xor(v, 1)); v = fmaxf(v, __shfl_xor(v, 2));
        v = fmaxf(v, __shfl_xor(v, 4)); v = fmaxf(v, __shfl_xor(v, 8));
        if (tid == 0) bcast[0] = v;
    }
    __syncthreads();
    m = bcast[0];
    float e0 = __expf(s0v - m), e1 = __expf(s1v - m);
    float ssum = e0 + e1;
    #pragma unroll
    for (int off = 32; off; off >>= 1) ssum += __shfl_xor(ssum, off);
    if (lane == 0) red[wave] = ssum;
    __syncthreads();
    if (tid < 16) {
        float v = red[tid];
        v += __shfl_xor(v, 1); v += __shfl_xor(v, 2);
        v += __shfl_xor(v, 4); v += __shfl_xor(v, 8);
        if (tid == 0) bcast[1] = v;
    }
    __syncthreads();
    const float inv = 1.f / bcast[1];
    const float c0 = e0 * inv, c1 = e1 * inv;
    out[(size_t)BB * NN + (size_t)b * NN + tid]        = c0;
    out[(size_t)BB * NN + (size_t)b * NN + tid + 1024] = c1;

    // ---- P7: directional conv + combine ----
    float dw0 = 0.f, dw1 = 0.f;
    #pragma unroll
    for (int d = 0; d < NTAP; d++) {
        float w = wd_s[d];
        dw0 = fmaf(w, r_s[(tid + 1024 + d) & (NN - 1)], dw0);
        dw1 = fmaf(w, r_s[(tid + d) & (NN - 1)], dw1);
    }
    out[2 * (size_t)BB * NN + (size_t)b * NN + tid]        = dw0;
    out[2 * (size_t)BB * NN + (size_t)b * NN + tid + 1024] = dw1;

    const float a0 = alloc_s[tid];
    const float a1 = alloc_s[tid + 1024];
    out[(size_t)b * NN + tid]        = gate * (0.5f * c0 + 0.5f * dw0 * a0);
    out[(size_t)b * NN + tid + 1024] = gate * (0.5f * c1 + 0.5f * dw1 * a1);
}

extern "C" void kernel_launch(void* const* d_in, const int* in_sizes, int n_in,
                              void* d_out, int out_size, void* d_ws, size_t ws_size,
                              hipStream_t stream) {
    const float* co    = (const float*)d_in[0];
    const float* rdw   = (const float*)d_in[1];
    const float* mem   = (const float*)d_in[3];
    const float* usage = (const float*)d_in[4];
    const float* Wk    = (const float*)d_in[5];
    const float* bk    = (const float*)d_in[6];
    const float* Wb    = (const float*)d_in[7];
    const float* bb    = (const float*)d_in[8];
    const float* Ws_   = (const float*)d_in[9];
    const float* bs    = (const float*)d_in[10];
    const float* Wg    = (const float*)d_in[11];
    const float* bg    = (const float*)d_in[12];
    float* out    = (float*)d_out;
    float* sim_ws = (float*)d_ws;

    hipLaunchKernelGGL(k_sim, dim3(256), dim3(1024), 0, stream,
                       co, mem, Wk, bk, sim_ws);
    hipLaunchKernelGGL(k_rest, dim3(BB), dim3(1024), 0, stream,
                       co, rdw, usage, sim_ws, Wb, bb, Ws_, bs, Wg, bg, out);
}

// Round 4
// 22.289 us; speedup vs baseline: 2.6109x; 1.2301x over previous
//
#include <hip/hip_runtime.h>

#define BB 32
#define NN 2048
#define WW 64
#define CC 1024
#define NTAP 17
#define NB 512
#define EPSF 1e-8f

// ws float layout
#define WS_X 0                       // [BB][NN] x = beta*sim
#define WS_Q (BB*NN)                 // [BB][NN] q = 0.5*gate*dir*alloc
#define WS_P (2*BB*NN)               // [BB][8][2] (m_seg, sumexp_seg)
#define WS_G (2*BB*NN + BB*16)       // [BB] gate

// ---------------------------------------------------------------------------
// K1: 288 blocks x 1024.
//  blocks 0..31  (b = bid): alloc (counting-bin, exact vs stable argsort) +
//                shift/gate dots + directional conv -> out2, out3, ws q/gate
//  blocks 32..287: k/beta projection + sim -> ws x, per-segment softmax partials
// ---------------------------------------------------------------------------
__global__ __launch_bounds__(1024) void k1(
    const float* __restrict__ co, const float* __restrict__ rdw,
    const float* __restrict__ usage, const float* __restrict__ mem,
    const float* __restrict__ Wk, const float* __restrict__ bk,
    const float* __restrict__ Wb, const float* __restrict__ bb,
    const float* __restrict__ Ws, const float* __restrict__ bs,
    const float* __restrict__ Wg, const float* __restrict__ bg,
    float* __restrict__ ws, float* __restrict__ out)
{
    __shared__ float co_s[CC];                 // 4 KB (both paths)
    __shared__ __align__(16) float k_s[WW];    // sim path
    __shared__ float r_s[NN];                  // 8 KB alloc path
    __shared__ unsigned long long skey[NN];    // 16 KB
    __shared__ float slog[NN];                 // 8 KB (sim path reuses as x-stash)
    __shared__ float alloc_s[NN];              // 8 KB
    __shared__ unsigned hist[NB];              // 2 KB
    __shared__ float binlog[NB];               // 2 KB
    __shared__ unsigned binStart[NB];          // 2 KB
    __shared__ unsigned cursor[NB];            // 2 KB
    __shared__ float binpre[NB];               // 2 KB
    __shared__ unsigned uw[8];
    __shared__ float fw[8];
    __shared__ float dot4[16][4];
    __shared__ float sred[16];
    __shared__ float scalars[8];
    __shared__ float wd_s[NTAP];

    const int tid = threadIdx.x, wave = tid >> 6, lane = tid & 63;

    if (blockIdx.x < BB) {
        // ======================= alloc + dots + dir =======================
        const int b = blockIdx.x;
        // P0a: zero + loads
        if (tid < NB) { hist[tid] = 0u; binlog[tid] = 0.f; }
        co_s[tid] = co[(size_t)b * CC + tid];
        r_s[tid]        = rdw[(size_t)b * NN + tid];
        r_s[tid + 1024] = rdw[(size_t)b * NN + tid + 1024];
        float u0 = usage[(size_t)b * NN + tid];
        float u1 = usage[(size_t)b * NN + tid + 1024];
        __syncthreads();
        // P0b: hist/logsum atomics + 4 scalar-dot partials (1 chunk per wave)
        float lg0 = log1pf(-u0), lg1 = log1pf(-u1);
        int bin0 = (int)(u0 * NB); bin0 = bin0 < 0 ? 0 : (bin0 > NB - 1 ? NB - 1 : bin0);
        int bin1 = (int)(u1 * NB); bin1 = bin1 < 0 ? 0 : (bin1 > NB - 1 ? NB - 1 : bin1);
        atomicAdd(&hist[bin0], 1u); atomicAdd(&binlog[bin0], lg0);
        atomicAdd(&hist[bin1], 1u); atomicAdd(&binlog[bin1], lg1);
        {
            float cv = co_s[tid];
            float p0 = cv * Ws[tid], p1 = cv * Ws[CC + tid],
                  p2 = cv * Ws[2 * CC + tid], p3 = cv * Wg[tid];
            #pragma unroll
            for (int off = 32; off; off >>= 1) {
                p0 += __shfl_xor(p0, off); p1 += __shfl_xor(p1, off);
                p2 += __shfl_xor(p2, off); p3 += __shfl_xor(p3, off);
            }
            if (lane == 0) {
                dot4[wave][0] = p0; dot4[wave][1] = p1;
                dot4[wave][2] = p2; dot4[wave][3] = p3;
            }
        }
        __syncthreads();
        // S1: dual wave-scan (hist u32, binlog f32) + finish scalar dots
        unsigned hv = 0u; float bv = 0.f, fi = 0.f; unsigned ui = 0u;
        if (tid < NB) {
            hv = hist[tid]; bv = binlog[tid];
            ui = hv; fi = bv;
            #pragma unroll
            for (int off = 1; off < 64; off <<= 1) {
                unsigned tu = __shfl_up(ui, off);
                float    tf = __shfl_up(fi, off);
                if (lane >= off) { ui += tu; fi += tf; }
            }
            if (lane == 63) { uw[wave] = ui; fw[wave] = fi; }
        }
        if (tid < 4) {
            float s = 0.f;
            #pragma unroll
            for (int w = 0; w < 16; w++) s += dot4[w][tid];
            scalars[tid] = s + ((tid < 3) ? bs[tid] : bg[0]);
        }
        __syncthreads();
        // S2: cross-wave scan (8 entries) || gate + taps on lane 16
        if (tid < 8) {
            unsigned v = uw[tid]; float f = fw[tid];
            #pragma unroll
            for (int off = 1; off < 8; off <<= 1) {
                unsigned tu = __shfl_up(v, off);
                float    tf = __shfl_up(f, off);
                if (tid >= off) { v += tu; f += tf; }
            }
            uw[tid] = v; fw[tid] = f;
        } else if (tid == 16) {
            float g = scalars[3];
            float gate = 1.f / (1.f + __expf(-g));
            scalars[6] = gate;
            ws[WS_G + b] = gate;
            float s0 = scalars[0], s1 = scalars[1], s2 = scalars[2];
            float m = fmaxf(s0, fmaxf(s1, s2));
            float e0 = __expf(s0 - m), e1 = __expf(s1 - m), e2 = __expf(s2 - m);
            float inv = 1.f / (e0 + e1 + e2);
            float sc = (e2 - e0) * inv;
            float den = 2.f * sc * sc + EPSF;
            float w[NTAP]; float S = 0.f;
            #pragma unroll
            for (int d = 0; d < NTAP; d++) { w[d] = __expf(-(float)(d * d) / den); S += w[d]; }
            float invS = 1.f / (S + EPSF);
            #pragma unroll
            for (int d = 0; d < NTAP; d++) wd_s[d] = w[d] * invS;
        }
        __syncthreads();
        // S3: per-bin bases (exclusive prefixes)
        if (tid < NB) {
            unsigned woff = wave ? uw[wave - 1] : 0u;
            float    foff = wave ? fw[wave - 1] : 0.f;
            unsigned st = woff + ui - hv;
            binStart[tid] = st; cursor[tid] = st;
            binpre[tid] = foff + fi - bv;
        }
        __syncthreads();
        // P3: scatter (key, log) into bin segments
        unsigned long long key0 = ((unsigned long long)__float_as_uint(u0) << 32) | (unsigned)tid;
        unsigned long long key1 = ((unsigned long long)__float_as_uint(u1) << 32) | (unsigned)(tid + 1024);
        {
            unsigned p0 = atomicAdd(&cursor[bin0], 1u);
            skey[p0] = key0; slog[p0] = lg0;
            unsigned p1 = atomicAdd(&cursor[bin1], 1u);
            skey[p1] = key1; slog[p1] = lg1;
        }
        __syncthreads();
        // P5: per-position masked sums -> alloc
        float* aout = out + 3 * (size_t)BB * NN + (size_t)b * NN;
        #pragma unroll
        for (int pp = 0; pp < 2; pp++) {
            int p = tid + pp * 1024;
            unsigned long long kp = skey[p];
            float up = __uint_as_float((unsigned)(kp >> 32));
            int c = (int)(up * NB); c = c < 0 ? 0 : (c > NB - 1 ? NB - 1 : c);
            unsigned st = binStart[c], cnt = hist[c];
            float s = binpre[c];
            for (unsigned q = 0; q < cnt; q++)
                s += (skey[st + q] <= kp) ? slog[st + q] : 0.f;
            float a = __expf(s);
            unsigned idx = (unsigned)(kp & 0xFFFFFFFFu);
            alloc_s[idx] = a;
            aout[idx] = a;
        }
        __syncthreads();
        // P7: directional conv + q staging
        const float gate = scalars[6];
        float dw0 = 0.f, dw1 = 0.f;
        #pragma unroll
        for (int d = 0; d < NTAP; d++) {
            float w = wd_s[d];
            dw0 = fmaf(w, r_s[(tid + 1024 + d) & (NN - 1)], dw0);
            dw1 = fmaf(w, r_s[(tid + d) & (NN - 1)], dw1);
        }
        out[2 * (size_t)BB * NN + (size_t)b * NN + tid]        = dw0;
        out[2 * (size_t)BB * NN + (size_t)b * NN + tid + 1024] = dw1;
        ws[WS_Q + (size_t)b * NN + tid]        = 0.5f * gate * dw0 * alloc_s[tid];
        ws[WS_Q + (size_t)b * NN + tid + 1024] = 0.5f * gate * dw1 * alloc_s[tid + 1024];
    } else {
        // ======================= sim path =======================
        const int idx = blockIdx.x - BB;
        const int b = idx >> 3, seg = idx & 7;
        co_s[tid] = co[(size_t)b * CC + tid];
        __syncthreads();
        for (int o = wave; o < 65; o += 16) {
            const float* row = (o < 64) ? (Wk + (size_t)o * CC) : Wb;
            float s = 0.f;
            #pragma unroll 4
            for (int c = lane; c < CC; c += 64) s = fmaf(co_s[c], row[c], s);
            #pragma unroll
            for (int off = 32; off; off >>= 1) s += __shfl_xor(s, off);
            if (lane == 0) {
                if (o < 64) k_s[o] = tanhf(s + bk[o]);
                else        scalars[0] = s + bb[0];
            }
        }
        __syncthreads();
        float xb = scalars[0];
        const float beta = (xb > 20.f) ? xb : log1pf(__expf(xb));
        const int lane16 = tid & 15, group = tid >> 4;
        const float4 k4 = *reinterpret_cast<const float4*>(&k_s[lane16 * 4]);
        #pragma unroll
        for (int it = 0; it < 4; it++) {
            int row = seg * 256 + it * 64 + group;
            const float4 m4 = *reinterpret_cast<const float4*>(
                mem + ((size_t)b * NN + row) * WW + lane16 * 4);
            float s = m4.x * k4.x + m4.y * k4.y + m4.z * k4.z + m4.w * k4.w;
            s += __shfl_xor(s, 1); s += __shfl_xor(s, 2);
            s += __shfl_xor(s, 4); s += __shfl_xor(s, 8);
            if (lane16 == 0) {
                float x = s * beta;
                slog[it * 64 + group] = x;          // stash for partials
                ws[WS_X + (size_t)b * NN + row] = x;
            }
        }
        __syncthreads();
        // per-segment softmax partials (m, sumexp) over the 256 stashed x
        float v = 0.f;
        if (tid < 256) {
            v = slog[tid];
            float m = v;
            #pragma unroll
            for (int off = 32; off; off >>= 1) m = fmaxf(m, __shfl_xor(m, off));
            if (lane == 0) sred[wave] = m;
        }
        __syncthreads();
        if (tid == 0) sred[8] = fmaxf(fmaxf(sred[0], sred[1]), fmaxf(sred[2], sred[3]));
        __syncthreads();
        if (tid < 256) {
            float e = __expf(v - sred[8]);
            #pragma unroll
            for (int off = 32; off; off >>= 1) e += __shfl_xor(e, off);
            if (lane == 0) sred[wave] = e;
        }
        __syncthreads();
        if (tid == 0) {
            ws[WS_P + ((size_t)b * 8 + seg) * 2]     = sred[8];
            ws[WS_P + ((size_t)b * 8 + seg) * 2 + 1] = sred[0] + sred[1] + sred[2] + sred[3];
        }
    }
}

// ---------------------------------------------------------------------------
// K2: 256 blocks x 256. Combine segment partials -> content + final write_weights.
// ---------------------------------------------------------------------------
__global__ __launch_bounds__(256) void k2(const float* __restrict__ ws,
                                          float* __restrict__ out)
{
    const int bid = blockIdx.x, b = bid >> 3, seg = bid & 7, tid = threadIdx.x;
    const float* part = ws + WS_P + (size_t)b * 16;
    float m = part[0];
    #pragma unroll
    for (int s8 = 1; s8 < 8; s8++) m = fmaxf(m, part[s8 * 2]);
    float denom = 0.f;
    #pragma unroll
    for (int s8 = 0; s8 < 8; s8++) denom += part[s8 * 2 + 1] * __expf(part[s8 * 2] - m);
    const float invd = 1.f / denom;
    const float gate = ws[WS_G + b];
    const int n = seg * 256 + tid;
    float x = ws[WS_X + (size_t)b * NN + n];
    float c = __expf(x - m) * invd;
    out[(size_t)BB * NN + (size_t)b * NN + n] = c;
    out[(size_t)b * NN + n] = fmaf(0.5f * gate, c, ws[WS_Q + (size_t)b * NN + n]);
}

extern "C" void kernel_launch(void* const* d_in, const int* in_sizes, int n_in,
                              void* d_out, int out_size, void* d_ws, size_t ws_size,
                              hipStream_t stream) {
    const float* co    = (const float*)d_in[0];
    const float* rdw   = (const float*)d_in[1];
    const float* mem   = (const float*)d_in[3];
    const float* usage = (const float*)d_in[4];
    const float* Wk    = (const float*)d_in[5];
    const float* bk    = (const float*)d_in[6];
    const float* Wb    = (const float*)d_in[7];
    const float* bb    = (const float*)d_in[8];
    const float* Ws_   = (const float*)d_in[9];
    const float* bs    = (const float*)d_in[10];
    const float* Wg    = (const float*)d_in[11];
    const float* bg    = (const float*)d_in[12];
    float* out = (float*)d_out;
    float* wsf = (float*)d_ws;

    hipLaunchKernelGGL(k1, dim3(BB + 256), dim3(1024), 0, stream,
                       co, rdw, usage, mem, Wk, bk, Wb, bb, Ws_, bs, Wg, bg,
                       wsf, out);
    hipLaunchKernelGGL(k2, dim3(256), dim3(256), 0, stream, wsf, out);
}